// Round 9
// baseline (159.662 us; speedup 1.0000x reference)
//
#include <hip/hip_runtime.h>
#include <cstdint>
#include <cstddef>

// GlobalAttention (Luong 'general'): q = src@W^T ; x = q@MB^T ; softmax(mask) ; c = P@MB
// Outputs: d_out = [ c (8*1024*256) | align_vectors (8*1024*4096) ] fp32.
// Pipeline: k_qproj -> k_logits3 (QK^T-swapped + float4 x-store + online stats)
//        -> k_stats -> k_pv (x->p in place + PV, fp16 split-K) -> k_csum
//
// R9: logits3's 53-us store overhead was store-pattern, not write BW (k_pv writes
// the same 134 MB inside a 38-us kernel). logits3-T: swapped MFMA operands give
// xT fragments where each lane holds 4 CONSECUTIVE s for fixed t=lc -> float4
// stores (4x fewer store instrs to drain at barriers); cheaper cross-q stats
// reduction; grid 1024 / 4 blocks/CU to cover the vmcnt(0) barrier drains.

typedef _Float16 f16;
typedef _Float16 half8 __attribute__((ext_vector_type(8)));
typedef _Float16 half4v __attribute__((ext_vector_type(4)));
typedef float f32x4 __attribute__((ext_vector_type(4)));

#define MFMA16(a, b, c) __builtin_amdgcn_mfma_f32_16x16x32_f16((a), (b), (c), 0, 0, 0)

static constexpr int NBATCH = 8;
static constexpr int NT = 1024;   // TGT
static constexpr int NS = 4096;   // SRC
static constexpr int ND = 256;    // SDIM == TDIM
static constexpr float NEGBIG = -3.0e38f;

__device__ __forceinline__ int swz(int row, int byteInRow) {
  return byteInRow ^ ((row & 7) << 4);
}

// ---------------- K1: q16 = source @ W^T (fp16 out) ----------------
__global__ __launch_bounds__(256) void k_qproj(const float* __restrict__ src,
                                               const float* __restrict__ W,
                                               f16* __restrict__ q16) {
  __shared__ __align__(16) f16 As[64 * 64];
  __shared__ __align__(16) f16 Bs[256 * 64];
  const int tid = threadIdx.x;
  const int w = tid >> 6, l = tid & 63;
  const int wt = w >> 1, wn = w & 1;
  const int q = l >> 4, lc = l & 15;
  const int t0 = blockIdx.x * 64;

  f32x4 acc[2][8];
#pragma unroll
  for (int i = 0; i < 2; ++i)
#pragma unroll
    for (int j = 0; j < 8; ++j) acc[i][j] = (f32x4){0.f, 0.f, 0.f, 0.f};

  for (int k0 = 0; k0 < 256; k0 += 64) {
    __syncthreads();
    {
      const int r = tid >> 2, c2 = (tid & 3) * 2;
      const float* g = src + (size_t)(t0 + r) * 256 + k0 + c2 * 8;
      float4 f0 = ((const float4*)g)[0], f1 = ((const float4*)g)[1];
      float4 f2 = ((const float4*)g)[2], f3 = ((const float4*)g)[3];
      half8 h0 = {(f16)f0.x, (f16)f0.y, (f16)f0.z, (f16)f0.w,
                  (f16)f1.x, (f16)f1.y, (f16)f1.z, (f16)f1.w};
      half8 h1 = {(f16)f2.x, (f16)f2.y, (f16)f2.z, (f16)f2.w,
                  (f16)f3.x, (f16)f3.y, (f16)f3.z, (f16)f3.w};
      *(half8*)((char*)As + r * 128 + swz(r, c2 * 16)) = h0;
      *(half8*)((char*)As + r * 128 + swz(r, c2 * 16 + 16)) = h1;
    }
    {
      const int n = tid;
      const float* g = W + (size_t)n * 256 + k0;
#pragma unroll
      for (int c = 0; c < 8; ++c) {
        float4 f0 = ((const float4*)(g + c * 8))[0];
        float4 f1 = ((const float4*)(g + c * 8))[1];
        half8 h = {(f16)f0.x, (f16)f0.y, (f16)f0.z, (f16)f0.w,
                   (f16)f1.x, (f16)f1.y, (f16)f1.z, (f16)f1.w};
        *(half8*)((char*)Bs + n * 128 + swz(n, c * 16)) = h;
      }
    }
    __syncthreads();
    half8 a[2][2], bb[8][2];
#pragma unroll
    for (int mb = 0; mb < 2; ++mb)
#pragma unroll
      for (int kf = 0; kf < 2; ++kf) {
        const int r = wt * 32 + mb * 16 + lc;
        a[mb][kf] = *(const half8*)((const char*)As + r * 128 + swz(r, kf * 64 + q * 16));
      }
#pragma unroll
    for (int nb = 0; nb < 8; ++nb)
#pragma unroll
      for (int kf = 0; kf < 2; ++kf) {
        const int r = wn * 128 + nb * 16 + lc;
        bb[nb][kf] = *(const half8*)((const char*)Bs + r * 128 + swz(r, kf * 64 + q * 16));
      }
#pragma unroll
    for (int kf = 0; kf < 2; ++kf)
#pragma unroll
      for (int mb = 0; mb < 2; ++mb)
#pragma unroll
        for (int nb = 0; nb < 8; ++nb)
          acc[mb][nb] = MFMA16(a[mb][kf], bb[nb][kf], acc[mb][nb]);
  }
#pragma unroll
  for (int mb = 0; mb < 2; ++mb)
#pragma unroll
    for (int nb = 0; nb < 8; ++nb)
#pragma unroll
      for (int j = 0; j < 4; ++j) {
        const int t = t0 + wt * 32 + mb * 16 + q * 4 + j;
        const int n = wn * 128 + nb * 16 + lc;
        q16[(size_t)t * 256 + n] = (f16)acc[mb][nb][j];
      }
}

// ---------------- K2: QK (swapped -> xT frags) + float4 x-store + online stats ----
// flat grid 1024: b = bid&7 (XCD pin), sc = (bid>>3)&7 (512-s), tt = bid>>6 (64-t).
// block 256 = 4 waves x 16 t-rows. Lane holds x[t=lc][s=q*4+j] -> float4 stores.
__global__ __launch_bounds__(256, 4) void k_logits3(const float* __restrict__ mbank,
                                                    const f16* __restrict__ q16,
                                                    const int* __restrict__ mask,
                                                    float* __restrict__ alignv,
                                                    float* __restrict__ pstats) {
  __shared__ __align__(16) f16 Bs[64 * 256];  // [s][d] f16, 512B rows, swizzled (32 KB)
  const int tid = threadIdx.x;
  const int w = tid >> 6, l = tid & 63;
  const int q = l >> 4, lc = l & 15;
  const int bid = blockIdx.x;
  const int b = bid & 7;
  const int sc = (bid >> 3) & 7;
  const int tt = bid >> 6;
  const int t0 = tt * 64;
  const int s0 = sc * 512;

  // q fragments for this wave's 16 t-rows (B-operand role)
  half8 aq[8];
  {
    const f16* qrow = q16 + (size_t)(b * NT + t0 + w * 16 + lc) * 256;
#pragma unroll
    for (int kf = 0; kf < 8; ++kf)
      aq[kf] = *(const half8*)(qrow + kf * 32 + q * 8);
  }

  const int t = t0 + w * 16 + lc;  // this lane's t-row
  float* abase = alignv + ((size_t)b * NT + t) * NS;

  float mrun = NEGBIG, lrun = 0.f;

  const int br = tid >> 2;
  const int cb = (tid & 3) * 64;
  for (int st = 0; st < 8; ++st) {
    const int sb = s0 + st * 64;
    __syncthreads();
    {  // stage Bs[64][256] fp32 -> f16 (proven fstats path)
      const float4* g = (const float4*)(mbank + ((size_t)b * NS + sb + br) * ND + cb);
#pragma unroll
      for (int i = 0; i < 8; ++i) {
        float4 f0 = g[2 * i], f1 = g[2 * i + 1];
        half8 h = {(f16)f0.x, (f16)f0.y, (f16)f0.z, (f16)f0.w,
                   (f16)f1.x, (f16)f1.y, (f16)f1.z, (f16)f1.w};
        *(half8*)((char*)Bs + br * 512 + swz(br, cb * 2 + i * 16)) = h;
      }
    }
    __syncthreads();
    // xT[nb] = mb_frag * q_frag : C[s][t], lane holds s = q*4+j for t = lc
    f32x4 xT[4];
#pragma unroll
    for (int i = 0; i < 4; ++i) xT[i] = (f32x4){0.f, 0.f, 0.f, 0.f};
#pragma unroll
    for (int kf = 0; kf < 8; ++kf)
#pragma unroll
      for (int nb = 0; nb < 4; ++nb) {
        const int rs = nb * 16 + lc;
        half8 mbf = *(const half8*)((const char*)Bs + rs * 512 + swz(rs, kf * 64 + q * 16));
        xT[nb] = MFMA16(mbf, aq[kf], xT[nb]);
      }
    // mask -> v, float4 store, stats
    float v[4][4];
#pragma unroll
    for (int nb = 0; nb < 4; ++nb) {
      const int4 mk = *(const int4*)(mask + (size_t)b * NS + sb + nb * 16 + q * 4);
      v[nb][0] = mk.x ? xT[nb][0] : NEGBIG;
      v[nb][1] = mk.y ? xT[nb][1] : NEGBIG;
      v[nb][2] = mk.z ? xT[nb][2] : NEGBIG;
      v[nb][3] = mk.w ? xT[nb][3] : NEGBIG;
      *(float4*)(abase + sb + nb * 16 + q * 4) =
          (float4){v[nb][0], v[nb][1], v[nb][2], v[nb][3]};
    }
    float m2 = NEGBIG;
#pragma unroll
    for (int nb = 0; nb < 4; ++nb)
#pragma unroll
      for (int j = 0; j < 4; ++j) m2 = fmaxf(m2, v[nb][j]);
    m2 = fmaxf(m2, __shfl_xor(m2, 16));
    m2 = fmaxf(m2, __shfl_xor(m2, 32));
    float s2 = 0.f;
#pragma unroll
    for (int nb = 0; nb < 4; ++nb)
#pragma unroll
      for (int j = 0; j < 4; ++j) s2 += __expf(v[nb][j] - m2);
    s2 += __shfl_xor(s2, 16);
    s2 += __shfl_xor(s2, 32);
    const float mn = fmaxf(mrun, m2);
    lrun = lrun * __expf(mrun - mn) + s2 * __expf(m2 - mn);
    mrun = mn;
  }
  if (l < 16) {
    pstats[(((size_t)b * NT + t) * 8 + sc) * 2 + 0] = mrun;
    pstats[(((size_t)b * NT + t) * 8 + sc) * 2 + 1] = lrun;
  }
}

// ---------------- K3: reduce 8 chunk partials -> m, 1/l per row ----------------
__global__ __launch_bounds__(256) void k_stats(const float* __restrict__ pstats,
                                               float* __restrict__ sm,
                                               float* __restrict__ slinv) {
  const int r = blockIdx.x * 256 + threadIdx.x;
  const float4* p = (const float4*)(pstats + (size_t)r * 16);
  float4 v[4];
  float mm = NEGBIG;
#pragma unroll
  for (int i = 0; i < 4; ++i) {
    v[i] = p[i];
    mm = fmaxf(mm, fmaxf(v[i].x, v[i].z));
  }
  float ll = 0.f;
#pragma unroll
  for (int i = 0; i < 4; ++i)
    ll += v[i].y * __expf(v[i].x - mm) + v[i].w * __expf(v[i].z - mm);
  sm[r] = mm;
  slinv[r] = (ll > 0.f) ? (1.f / ll) : 0.f;
}

// ---------------- K4: p = exp(x-m)/l (once per element, in place) ; partial c = P@V ----
// R4's measured-fast kernel; flat grid 512 with b = bid&7 XCD pin.
__global__ __launch_bounds__(512, 4) void k_pv(const float* __restrict__ mbank,
                                               const float* __restrict__ sm,
                                               const float* __restrict__ slinv,
                                               float* __restrict__ alignv,
                                               f16* __restrict__ pc) {
  __shared__ __align__(16) f16 VT[256 * 64];
  __shared__ __align__(16) f16 Ps[64 * 64];
  const int tid = threadIdx.x;
  const int w = tid >> 6, l = tid & 63;
  const int wtg = w >> 2, wd = w & 3;
  const int q = l >> 4, lc = l & 15;
  const int bid = blockIdx.x;
  const int b = bid & 7;
  const int kc = (bid >> 3) & 3;
  const int tt = bid >> 5;
  const int t0 = tt * 64;
  const int s0 = kc * 1024;

  const int pt = tid >> 3;
  const int ps8 = (tid & 7) * 8;
  const float mv = sm[(size_t)b * NT + t0 + pt];
  const float lv = slinv[(size_t)b * NT + t0 + pt];
  float* xrow = alignv + ((size_t)b * NT + t0 + pt) * NS + s0 + ps8;

  f32x4 acc[2][4];
#pragma unroll
  for (int i = 0; i < 2; ++i)
#pragma unroll
    for (int j = 0; j < 4; ++j) acc[i][j] = (f32x4){0.f, 0.f, 0.f, 0.f};

  const int dstage = (w & 3) * 64 + l;
  const int shalf = (w >> 2) * 32;

  float4 xA = ((const float4*)xrow)[0];
  float4 xB = ((const float4*)xrow)[1];

  for (int st = 0; st < 16; ++st) {
    const int sb = s0 + st * 64;
    __syncthreads();
    {
#pragma unroll
      for (int i = 0; i < 8; ++i) {
        const int s4 = shalf + i * 4;
        const float* g = mbank + ((size_t)b * NS + sb + s4) * ND + dstage;
        const float f0 = g[0], f1 = g[ND], f2 = g[2 * ND], f3 = g[3 * ND];
        half4v h = {(f16)f0, (f16)f1, (f16)f2, (f16)f3};
        *(half4v*)((char*)VT + dstage * 128 + swz(dstage, s4 * 2)) = h;
      }
    }
    {
      const float p0 = __expf(xA.x - mv) * lv, p1 = __expf(xA.y - mv) * lv;
      const float p2 = __expf(xA.z - mv) * lv, p3 = __expf(xA.w - mv) * lv;
      const float p4 = __expf(xB.x - mv) * lv, p5 = __expf(xB.y - mv) * lv;
      const float p6 = __expf(xB.z - mv) * lv, p7 = __expf(xB.w - mv) * lv;
      float* xp = xrow + st * 64;
      ((float4*)xp)[0] = (float4){p0, p1, p2, p3};
      ((float4*)xp)[1] = (float4){p4, p5, p6, p7};
      half8 h = {(f16)p0, (f16)p1, (f16)p2, (f16)p3,
                 (f16)p4, (f16)p5, (f16)p6, (f16)p7};
      *(half8*)((char*)Ps + pt * 128 + swz(pt, ps8 * 2)) = h;
    }
    if (st < 15) {
      const float* xn = xrow + (st + 1) * 64;
      xA = ((const float4*)xn)[0];
      xB = ((const float4*)xn)[1];
    }
    __syncthreads();
    half8 a[2][2];
#pragma unroll
    for (int mb = 0; mb < 2; ++mb)
#pragma unroll
      for (int kf = 0; kf < 2; ++kf) {
        const int r = wtg * 32 + mb * 16 + lc;
        a[mb][kf] = *(const half8*)((const char*)Ps + r * 128 + swz(r, kf * 64 + q * 16));
      }
#pragma unroll
    for (int kf = 0; kf < 2; ++kf)
#pragma unroll
      for (int nb = 0; nb < 4; ++nb) {
        const int d = wd * 64 + nb * 16 + lc;
        half8 bbt = *(const half8*)((const char*)VT + d * 128 + swz(d, kf * 64 + q * 16));
#pragma unroll
        for (int mb = 0; mb < 2; ++mb)
          acc[mb][nb] = MFMA16(a[mb][kf], bbt, acc[mb][nb]);
      }
  }

#pragma unroll
  for (int mb = 0; mb < 2; ++mb)
#pragma unroll
    for (int nb = 0; nb < 4; ++nb)
#pragma unroll
      for (int j = 0; j < 4; ++j) {
        const int t = t0 + wtg * 32 + mb * 16 + q * 4 + j;
        const int d = wd * 64 + nb * 16 + lc;
        pc[(size_t)kc * ((size_t)NBATCH * NT * ND) + ((size_t)b * NT + t) * ND + d] =
            (f16)acc[mb][nb][j];
      }
}

// ---------------- K5: c = sum of 4 fp16 split-K partials ----------------
__global__ __launch_bounds__(256) void k_csum(const f16* __restrict__ pc,
                                              float* __restrict__ outc) {
  const size_t i8 = ((size_t)blockIdx.x * 256 + threadIdx.x) * 8;
  const size_t STRIDE = (size_t)NBATCH * NT * ND;
  half8 a = *(const half8*)(pc + i8);
  half8 b = *(const half8*)(pc + STRIDE + i8);
  half8 c = *(const half8*)(pc + 2 * STRIDE + i8);
  half8 d = *(const half8*)(pc + 3 * STRIDE + i8);
  float4 r0, r1;
  r0.x = (float)a[0] + (float)b[0] + (float)c[0] + (float)d[0];
  r0.y = (float)a[1] + (float)b[1] + (float)c[1] + (float)d[1];
  r0.z = (float)a[2] + (float)b[2] + (float)c[2] + (float)d[2];
  r0.w = (float)a[3] + (float)b[3] + (float)c[3] + (float)d[3];
  r1.x = (float)a[4] + (float)b[4] + (float)c[4] + (float)d[4];
  r1.y = (float)a[5] + (float)b[5] + (float)c[5] + (float)d[5];
  r1.z = (float)a[6] + (float)b[6] + (float)c[6] + (float)d[6];
  r1.w = (float)a[7] + (float)b[7] + (float)c[7] + (float)d[7];
  *(float4*)(outc + i8) = r0;
  *(float4*)(outc + i8 + 4) = r1;
}

extern "C" void kernel_launch(void* const* d_in, const int* in_sizes, int n_in,
                              void* d_out, int out_size, void* d_ws, size_t ws_size,
                              hipStream_t stream) {
  const float* mbank = (const float*)d_in[0];  // (8,4096,256) f32
  const float* src   = (const float*)d_in[1];  // (8,1024,256) f32
  const int*   mask  = (const int*)d_in[2];    // (8,4096) bool->int
  const float* W     = (const float*)d_in[3];  // (256,256) f32

  float* out_c = (float*)d_out;
  float* out_align = out_c + (size_t)NBATCH * NT * ND;

  // ws layout (24 MB total):
  //   [0, 4 MB)          q16   : 8192x256 fp16
  //   [4 MB, +512 KB)    pstats: 8192x8x2 f32
  //   [4.5 MB, +32 KB)   sm
  //   [4.5 MB+32K,+32K)  slinv
  //   [8 MB, 24 MB)      pc    : 4 x 2M fp16 split-K partials
  char* ws = (char*)d_ws;
  f16* q16      = (f16*)ws;
  float* pstats = (float*)(ws + (4 << 20));
  float* sm     = (float*)(ws + (4 << 20) + (512 << 10));
  float* slinv  = (float*)(ws + (4 << 20) + (544 << 10));
  f16* pc       = (f16*)(ws + (8 << 20));

  hipLaunchKernelGGL(k_qproj, dim3(128), dim3(256), 0, stream, src, W, q16);
  hipLaunchKernelGGL(k_logits3, dim3(1024), dim3(256), 0, stream,
                     mbank, q16, mask, out_align, pstats);
  hipLaunchKernelGGL(k_stats, dim3(32), dim3(256), 0, stream, pstats, sm, slinv);
  hipLaunchKernelGGL(k_pv, dim3(512), dim3(512), 0, stream,
                     mbank, sm, slinv, out_align, pc);
  hipLaunchKernelGGL(k_csum, dim3(1024), dim3(256), 0, stream, pc, out_c);
}

// Round 10
// 145.879 us; speedup vs baseline: 1.0945x; 1.0945x over previous
//
#include <hip/hip_runtime.h>
#include <cstdint>
#include <cstddef>

// GlobalAttention (Luong 'general'): q = src@W^T ; x = q@MB^T ; softmax(mask) ; c = P@MB
// Outputs: d_out = [ c (8*1024*256) | align_vectors (8*1024*4096) ] fp32.
// Pipeline: k_qproj -> k_logits5 (QK swapped + float4 x-store + online stats)
//        -> k_stats (16 chunks) -> k_pv (x->p in place + PV) -> k_csum
//
// R10: R9's t-64/1024-block logits doubled staging traffic + conflicts -> revert
// to R8's traffic geometry (t-tile 128, 512-s chunk, 512 blocks, 256 MB staging)
// but in k_pv's PROVEN 512-thread/8-wave shell (pv moves 545 MB in 38 us; the
// 8-wave block + few big stores tolerates barrier store-drains). Swapped-operand
// MFMA (validated R9) gives float4 x-stores: 4 per thread-step vs R8's 32 scalars.

typedef _Float16 f16;
typedef _Float16 half8 __attribute__((ext_vector_type(8)));
typedef _Float16 half4v __attribute__((ext_vector_type(4)));
typedef float f32x4 __attribute__((ext_vector_type(4)));

#define MFMA16(a, b, c) __builtin_amdgcn_mfma_f32_16x16x32_f16((a), (b), (c), 0, 0, 0)

static constexpr int NBATCH = 8;
static constexpr int NT = 1024;   // TGT
static constexpr int NS = 4096;   // SRC
static constexpr int ND = 256;    // SDIM == TDIM
static constexpr float NEGBIG = -3.0e38f;

__device__ __forceinline__ int swz(int row, int byteInRow) {
  return byteInRow ^ ((row & 7) << 4);
}

// ---------------- K1: q16 = source @ W^T (fp16 out) ----------------
__global__ __launch_bounds__(256) void k_qproj(const float* __restrict__ src,
                                               const float* __restrict__ W,
                                               f16* __restrict__ q16) {
  __shared__ __align__(16) f16 As[64 * 64];
  __shared__ __align__(16) f16 Bs[256 * 64];
  const int tid = threadIdx.x;
  const int w = tid >> 6, l = tid & 63;
  const int wt = w >> 1, wn = w & 1;
  const int q = l >> 4, lc = l & 15;
  const int t0 = blockIdx.x * 64;

  f32x4 acc[2][8];
#pragma unroll
  for (int i = 0; i < 2; ++i)
#pragma unroll
    for (int j = 0; j < 8; ++j) acc[i][j] = (f32x4){0.f, 0.f, 0.f, 0.f};

  for (int k0 = 0; k0 < 256; k0 += 64) {
    __syncthreads();
    {
      const int r = tid >> 2, c2 = (tid & 3) * 2;
      const float* g = src + (size_t)(t0 + r) * 256 + k0 + c2 * 8;
      float4 f0 = ((const float4*)g)[0], f1 = ((const float4*)g)[1];
      float4 f2 = ((const float4*)g)[2], f3 = ((const float4*)g)[3];
      half8 h0 = {(f16)f0.x, (f16)f0.y, (f16)f0.z, (f16)f0.w,
                  (f16)f1.x, (f16)f1.y, (f16)f1.z, (f16)f1.w};
      half8 h1 = {(f16)f2.x, (f16)f2.y, (f16)f2.z, (f16)f2.w,
                  (f16)f3.x, (f16)f3.y, (f16)f3.z, (f16)f3.w};
      *(half8*)((char*)As + r * 128 + swz(r, c2 * 16)) = h0;
      *(half8*)((char*)As + r * 128 + swz(r, c2 * 16 + 16)) = h1;
    }
    {
      const int n = tid;
      const float* g = W + (size_t)n * 256 + k0;
#pragma unroll
      for (int c = 0; c < 8; ++c) {
        float4 f0 = ((const float4*)(g + c * 8))[0];
        float4 f1 = ((const float4*)(g + c * 8))[1];
        half8 h = {(f16)f0.x, (f16)f0.y, (f16)f0.z, (f16)f0.w,
                   (f16)f1.x, (f16)f1.y, (f16)f1.z, (f16)f1.w};
        *(half8*)((char*)Bs + n * 128 + swz(n, c * 16)) = h;
      }
    }
    __syncthreads();
    half8 a[2][2], bb[8][2];
#pragma unroll
    for (int mb = 0; mb < 2; ++mb)
#pragma unroll
      for (int kf = 0; kf < 2; ++kf) {
        const int r = wt * 32 + mb * 16 + lc;
        a[mb][kf] = *(const half8*)((const char*)As + r * 128 + swz(r, kf * 64 + q * 16));
      }
#pragma unroll
    for (int nb = 0; nb < 8; ++nb)
#pragma unroll
      for (int kf = 0; kf < 2; ++kf) {
        const int r = wn * 128 + nb * 16 + lc;
        bb[nb][kf] = *(const half8*)((const char*)Bs + r * 128 + swz(r, kf * 64 + q * 16));
      }
#pragma unroll
    for (int kf = 0; kf < 2; ++kf)
#pragma unroll
      for (int mb = 0; mb < 2; ++mb)
#pragma unroll
        for (int nb = 0; nb < 8; ++nb)
          acc[mb][nb] = MFMA16(a[mb][kf], bb[nb][kf], acc[mb][nb]);
  }
#pragma unroll
  for (int mb = 0; mb < 2; ++mb)
#pragma unroll
    for (int nb = 0; nb < 8; ++nb)
#pragma unroll
      for (int j = 0; j < 4; ++j) {
        const int t = t0 + wt * 32 + mb * 16 + q * 4 + j;
        const int n = wn * 128 + nb * 16 + lc;
        q16[(size_t)t * 256 + n] = (f16)acc[mb][nb][j];
      }
}

// ---------------- K2: QK (swapped) + float4 x-store + online stats ----------
// flat grid 512: b = bid&7 (XCD pin), kc = (bid>>3)&7 (512-s chunk), tt = bid>>6
// (128-t tile). block 512 = 8 waves: tg = w>>1 owns 32 t-rows, sh = w&1 owns a
// 32-s half of each 64-s step. 8 steps. Lane stores 4x float4 per step.
__global__ __launch_bounds__(512, 4) void k_logits5(const float* __restrict__ mbank,
                                                    const f16* __restrict__ q16,
                                                    const int* __restrict__ mask,
                                                    float* __restrict__ alignv,
                                                    float* __restrict__ pstats) {
  __shared__ __align__(16) f16 Bs[64 * 256];  // [s][d] f16, 512B rows, swz (32 KB)
  const int tid = threadIdx.x;
  const int w = tid >> 6, l = tid & 63;
  const int q = l >> 4, lc = l & 15;
  const int bid = blockIdx.x;
  const int b = bid & 7;
  const int kc = (bid >> 3) & 7;
  const int tt = bid >> 6;
  const int t0 = tt * 128;
  const int s0 = kc * 512;
  const int tg = w >> 1;  // 0..3
  const int sh = w & 1;   // 0..1

  // q fragments (B-operand role) for this wave's 2 x 16 t-rows
  half8 aq[2][8];
#pragma unroll
  for (int mb = 0; mb < 2; ++mb) {
    const f16* qrow = q16 + (size_t)(b * NT + t0 + tg * 32 + mb * 16 + lc) * 256;
#pragma unroll
    for (int kf = 0; kf < 8; ++kf)
      aq[mb][kf] = *(const half8*)(qrow + kf * 32 + q * 8);
  }

  float mrun[2] = {NEGBIG, NEGBIG}, lrun[2] = {0.f, 0.f};

  const int br = tid >> 3;        // staging row 0..63
  const int cb = (tid & 7) * 32;  // f32 col base (8 float4)
  for (int st = 0; st < 8; ++st) {
    const int sb = s0 + st * 64;
    __syncthreads();  // prev MFMA done reading Bs
    {  // stage Bs[64][256] fp32 -> f16: 8 float4 loads, 4 half8 writes
      const float4* g = (const float4*)(mbank + ((size_t)b * NS + sb + br) * ND + cb);
      float4 f[8];
#pragma unroll
      for (int i = 0; i < 8; ++i) f[i] = g[i];
#pragma unroll
      for (int i = 0; i < 4; ++i) {
        half8 h = {(f16)f[2 * i].x, (f16)f[2 * i].y, (f16)f[2 * i].z, (f16)f[2 * i].w,
                   (f16)f[2 * i + 1].x, (f16)f[2 * i + 1].y, (f16)f[2 * i + 1].z,
                   (f16)f[2 * i + 1].w};
        *(half8*)((char*)Bs + br * 512 + swz(br, cb * 2 + i * 16)) = h;
      }
    }
    __syncthreads();  // Bs ready
    // xT[mb][nb] = mb_frag * q_frag : lane holds s = q*4+j (row), t = lc (col)
    f32x4 xT[2][2];
#pragma unroll
    for (int i = 0; i < 2; ++i)
#pragma unroll
      for (int j = 0; j < 2; ++j) xT[i][j] = (f32x4){0.f, 0.f, 0.f, 0.f};
#pragma unroll
    for (int kf = 0; kf < 8; ++kf)
#pragma unroll
      for (int nb = 0; nb < 2; ++nb) {
        const int rs = sh * 32 + nb * 16 + lc;
        half8 mbf = *(const half8*)((const char*)Bs + rs * 512 + swz(rs, kf * 64 + q * 16));
#pragma unroll
        for (int mb = 0; mb < 2; ++mb)
          xT[mb][nb] = MFMA16(mbf, aq[mb][kf], xT[mb][nb]);
      }
    // mask -> v -> float4 stores + stats
#pragma unroll
    for (int nb = 0; nb < 2; ++nb) {
      const int4 mk = *(const int4*)(mask + (size_t)b * NS + sb + sh * 32 + nb * 16 + q * 4);
#pragma unroll
      for (int mb = 0; mb < 2; ++mb) {
        float v0 = mk.x ? xT[mb][nb][0] : NEGBIG;
        float v1 = mk.y ? xT[mb][nb][1] : NEGBIG;
        float v2 = mk.z ? xT[mb][nb][2] : NEGBIG;
        float v3 = mk.w ? xT[mb][nb][3] : NEGBIG;
        const int t = t0 + tg * 32 + mb * 16 + lc;
        *(float4*)(alignv + ((size_t)b * NT + t) * NS + sb + sh * 32 + nb * 16 + q * 4) =
            (float4){v0, v1, v2, v3};
        float m2 = fmaxf(fmaxf(v0, v1), fmaxf(v2, v3));
        float s2l = __expf(v0 - m2) + __expf(v1 - m2) + __expf(v2 - m2) + __expf(v3 - m2);
        // carry into per-mb accumulators via online merge at nb granularity
        // (first reduce across q-groups below needs full 32-s; do per-nb here)
        // merge (m2, s2l) into running stats after cross-q reduce:
        // stash in v0 slot pattern: do reduce now
        m2 = fmaxf(m2, __shfl_xor(m2, 16));
        m2 = fmaxf(m2, __shfl_xor(m2, 32));
        float s2 = s2l * __expf((fmaxf(fmaxf(v0, v1), fmaxf(v2, v3))) - m2);
        s2 += __shfl_xor(s2, 16);
        s2 += __shfl_xor(s2, 32);
        const float mn = fmaxf(mrun[mb], m2);
        lrun[mb] = lrun[mb] * __expf(mrun[mb] - mn) + s2 * __expf(m2 - mn);
        mrun[mb] = mn;
      }
    }
  }
  if (l < 16) {
#pragma unroll
    for (int mb = 0; mb < 2; ++mb) {
      const int t = t0 + tg * 32 + mb * 16 + l;
      const int chunk = kc * 2 + sh;
      pstats[(((size_t)b * NT + t) * 16 + chunk) * 2 + 0] = mrun[mb];
      pstats[(((size_t)b * NT + t) * 16 + chunk) * 2 + 1] = lrun[mb];
    }
  }
}

// ---------------- K3: reduce 16 chunk partials -> m, 1/l per row ----------------
__global__ __launch_bounds__(256) void k_stats(const float* __restrict__ pstats,
                                               float* __restrict__ sm,
                                               float* __restrict__ slinv) {
  const int r = blockIdx.x * 256 + threadIdx.x;
  const float4* p = (const float4*)(pstats + (size_t)r * 32);
  float4 v[8];
  float mm = NEGBIG;
#pragma unroll
  for (int i = 0; i < 8; ++i) {
    v[i] = p[i];
    mm = fmaxf(mm, fmaxf(v[i].x, v[i].z));
  }
  float ll = 0.f;
#pragma unroll
  for (int i = 0; i < 8; ++i)
    ll += v[i].y * __expf(v[i].x - mm) + v[i].w * __expf(v[i].z - mm);
  sm[r] = mm;
  slinv[r] = (ll > 0.f) ? (1.f / ll) : 0.f;
}

// ---------------- K4: p = exp(x-m)/l (once per element, in place) ; partial c = P@V ----
// R4's measured-fast kernel; flat grid 512 with b = bid&7 XCD pin.
__global__ __launch_bounds__(512, 4) void k_pv(const float* __restrict__ mbank,
                                               const float* __restrict__ sm,
                                               const float* __restrict__ slinv,
                                               float* __restrict__ alignv,
                                               f16* __restrict__ pc) {
  __shared__ __align__(16) f16 VT[256 * 64];
  __shared__ __align__(16) f16 Ps[64 * 64];
  const int tid = threadIdx.x;
  const int w = tid >> 6, l = tid & 63;
  const int wtg = w >> 2, wd = w & 3;
  const int q = l >> 4, lc = l & 15;
  const int bid = blockIdx.x;
  const int b = bid & 7;
  const int kc = (bid >> 3) & 3;
  const int tt = bid >> 5;
  const int t0 = tt * 64;
  const int s0 = kc * 1024;

  const int pt = tid >> 3;
  const int ps8 = (tid & 7) * 8;
  const float mv = sm[(size_t)b * NT + t0 + pt];
  const float lv = slinv[(size_t)b * NT + t0 + pt];
  float* xrow = alignv + ((size_t)b * NT + t0 + pt) * NS + s0 + ps8;

  f32x4 acc[2][4];
#pragma unroll
  for (int i = 0; i < 2; ++i)
#pragma unroll
    for (int j = 0; j < 4; ++j) acc[i][j] = (f32x4){0.f, 0.f, 0.f, 0.f};

  const int dstage = (w & 3) * 64 + l;
  const int shalf = (w >> 2) * 32;

  float4 xA = ((const float4*)xrow)[0];
  float4 xB = ((const float4*)xrow)[1];

  for (int st = 0; st < 16; ++st) {
    const int sb = s0 + st * 64;
    __syncthreads();
    {
#pragma unroll
      for (int i = 0; i < 8; ++i) {
        const int s4 = shalf + i * 4;
        const float* g = mbank + ((size_t)b * NS + sb + s4) * ND + dstage;
        const float f0 = g[0], f1 = g[ND], f2 = g[2 * ND], f3 = g[3 * ND];
        half4v h = {(f16)f0, (f16)f1, (f16)f2, (f16)f3};
        *(half4v*)((char*)VT + dstage * 128 + swz(dstage, s4 * 2)) = h;
      }
    }
    {
      const float p0 = __expf(xA.x - mv) * lv, p1 = __expf(xA.y - mv) * lv;
      const float p2 = __expf(xA.z - mv) * lv, p3 = __expf(xA.w - mv) * lv;
      const float p4 = __expf(xB.x - mv) * lv, p5 = __expf(xB.y - mv) * lv;
      const float p6 = __expf(xB.z - mv) * lv, p7 = __expf(xB.w - mv) * lv;
      float* xp = xrow + st * 64;
      ((float4*)xp)[0] = (float4){p0, p1, p2, p3};
      ((float4*)xp)[1] = (float4){p4, p5, p6, p7};
      half8 h = {(f16)p0, (f16)p1, (f16)p2, (f16)p3,
                 (f16)p4, (f16)p5, (f16)p6, (f16)p7};
      *(half8*)((char*)Ps + pt * 128 + swz(pt, ps8 * 2)) = h;
    }
    if (st < 15) {
      const float* xn = xrow + (st + 1) * 64;
      xA = ((const float4*)xn)[0];
      xB = ((const float4*)xn)[1];
    }
    __syncthreads();
    half8 a[2][2];
#pragma unroll
    for (int mb = 0; mb < 2; ++mb)
#pragma unroll
      for (int kf = 0; kf < 2; ++kf) {
        const int r = wtg * 32 + mb * 16 + lc;
        a[mb][kf] = *(const half8*)((const char*)Ps + r * 128 + swz(r, kf * 64 + q * 16));
      }
#pragma unroll
    for (int kf = 0; kf < 2; ++kf)
#pragma unroll
      for (int nb = 0; nb < 4; ++nb) {
        const int d = wd * 64 + nb * 16 + lc;
        half8 bbt = *(const half8*)((const char*)VT + d * 128 + swz(d, kf * 64 + q * 16));
#pragma unroll
        for (int mb = 0; mb < 2; ++mb)
          acc[mb][nb] = MFMA16(a[mb][kf], bbt, acc[mb][nb]);
      }
  }

#pragma unroll
  for (int mb = 0; mb < 2; ++mb)
#pragma unroll
    for (int nb = 0; nb < 4; ++nb)
#pragma unroll
      for (int j = 0; j < 4; ++j) {
        const int t = t0 + wtg * 32 + mb * 16 + q * 4 + j;
        const int d = wd * 64 + nb * 16 + lc;
        pc[(size_t)kc * ((size_t)NBATCH * NT * ND) + ((size_t)b * NT + t) * ND + d] =
            (f16)acc[mb][nb][j];
      }
}

// ---------------- K5: c = sum of 4 fp16 split-K partials ----------------
__global__ __launch_bounds__(256) void k_csum(const f16* __restrict__ pc,
                                              float* __restrict__ outc) {
  const size_t i8 = ((size_t)blockIdx.x * 256 + threadIdx.x) * 8;
  const size_t STRIDE = (size_t)NBATCH * NT * ND;
  half8 a = *(const half8*)(pc + i8);
  half8 b = *(const half8*)(pc + STRIDE + i8);
  half8 c = *(const half8*)(pc + 2 * STRIDE + i8);
  half8 d = *(const half8*)(pc + 3 * STRIDE + i8);
  float4 r0, r1;
  r0.x = (float)a[0] + (float)b[0] + (float)c[0] + (float)d[0];
  r0.y = (float)a[1] + (float)b[1] + (float)c[1] + (float)d[1];
  r0.z = (float)a[2] + (float)b[2] + (float)c[2] + (float)d[2];
  r0.w = (float)a[3] + (float)b[3] + (float)c[3] + (float)d[3];
  r1.x = (float)a[4] + (float)b[4] + (float)c[4] + (float)d[4];
  r1.y = (float)a[5] + (float)b[5] + (float)c[5] + (float)d[5];
  r1.z = (float)a[6] + (float)b[6] + (float)c[6] + (float)d[6];
  r1.w = (float)a[7] + (float)b[7] + (float)c[7] + (float)d[7];
  *(float4*)(outc + i8) = r0;
  *(float4*)(outc + i8 + 4) = r1;
}

extern "C" void kernel_launch(void* const* d_in, const int* in_sizes, int n_in,
                              void* d_out, int out_size, void* d_ws, size_t ws_size,
                              hipStream_t stream) {
  const float* mbank = (const float*)d_in[0];  // (8,4096,256) f32
  const float* src   = (const float*)d_in[1];  // (8,1024,256) f32
  const int*   mask  = (const int*)d_in[2];    // (8,4096) bool->int
  const float* W     = (const float*)d_in[3];  // (256,256) f32

  float* out_c = (float*)d_out;
  float* out_align = out_c + (size_t)NBATCH * NT * ND;

  // ws layout (24 MB total):
  //   [0, 4 MB)          q16   : 8192x256 fp16
  //   [4 MB, 5 MB)       pstats: 8192x16x2 f32
  //   [5 MB, +32 KB)     sm
  //   [5 MB+32K, +32K)   slinv
  //   [8 MB, 24 MB)      pc    : 4 x 2M fp16 split-K partials
  char* ws = (char*)d_ws;
  f16* q16      = (f16*)ws;
  float* pstats = (float*)(ws + (4 << 20));
  float* sm     = (float*)(ws + (5 << 20));
  float* slinv  = (float*)(ws + (5 << 20) + (32 << 10));
  f16* pc       = (f16*)(ws + (8 << 20));

  hipLaunchKernelGGL(k_qproj, dim3(128), dim3(256), 0, stream, src, W, q16);
  hipLaunchKernelGGL(k_logits5, dim3(512), dim3(512), 0, stream,
                     mbank, q16, mask, out_align, pstats);
  hipLaunchKernelGGL(k_stats, dim3(32), dim3(256), 0, stream, pstats, sm, slinv);
  hipLaunchKernelGGL(k_pv, dim3(512), dim3(512), 0, stream,
                     mbank, sm, slinv, out_align, pc);
  hipLaunchKernelGGL(k_csum, dim3(1024), dim3(256), 0, stream, pc, out_c);
}